// Round 10
// baseline (18234.790 us; speedup 1.0000x reference)
//
#include <hip/hip_runtime.h>
#include <cstdint>

#define SSP   13294      // total spatial tokens (100^2+50^2+25^2+13^2)
#define NROW  2400       // B*NQ
#define NROWP 2432

__device__ __forceinline__ double sigd(double x) { return 1.0 / (1.0 + exp(-x)); }
__device__ __forceinline__ double invsigd(double x) {
    x = fmin(fmax(x, 0.0), 1.0);
    return log(fmax(x, 1e-5) / fmax(1.0 - x, 1e-5));
}
__device__ __forceinline__ double rdA(const float* a, size_t k) { return (double)a[k]; }
__device__ __forceinline__ double rdA(const double* a, size_t k) { return a[k]; }

// ---- LDS-tiled GEMM, fp64 math: C (+)= relu?(A(MxK) @ W(NxK)^T + bias) ------
template<typename TA, bool RELU, bool ACC>
__global__ __launch_bounds__(256)
void ngemm(const TA* __restrict__ A, int lda,
           const float* __restrict__ W, int ldb,
           const float* __restrict__ bias,
           float* __restrict__ C, int ldc,
           int M, int N, int K)
{
    __shared__ double As[32][33];
    __shared__ double Bs[32][33];
    int bm = blockIdx.x * 32, bn = blockIdx.y * 32;
    int tx = threadIdx.x & 15, ty = threadIdx.x >> 4;
    double a00 = 0., a01 = 0., a10 = 0., a11 = 0.;
    for (int k0 = 0; k0 < K; k0 += 32) {
        for (int e = threadIdx.x; e < 1024; e += 256) {
            int r = e >> 5, kk = e & 31;
            int am = bm + r; if (am > M - 1) am = M - 1;
            As[r][kk] = rdA(A, (size_t)am * lda + k0 + kk);
            int wn = bn + r; if (wn > N - 1) wn = N - 1;
            Bs[r][kk] = (double)W[(size_t)wn * ldb + k0 + kk];
        }
        __syncthreads();
        for (int kk = 0; kk < 32; kk++) {
            double x0 = As[ty * 2][kk], x1 = As[ty * 2 + 1][kk];
            double y0 = Bs[tx * 2][kk], y1 = Bs[tx * 2 + 1][kk];
            a00 += x0 * y0; a01 += x0 * y1;
            a10 += x1 * y0; a11 += x1 * y1;
        }
        __syncthreads();
    }
    double accv[2][2] = {{a00, a01}, {a10, a11}};
    for (int i = 0; i < 2; i++)
        for (int j = 0; j < 2; j++) {
            int gm = bm + ty * 2 + i, gn = bn + tx * 2 + j;
            if (gm < M && gn < N) {
                double v = accv[i][j] + (bias ? (double)bias[gn] : 0.0);
                if (ACC) v += (double)C[(size_t)gm * ldc + gn];
                if (RELU) v = fmax(v, 0.0);
                C[(size_t)gm * ldc + gn] = (float)v;
            }
        }
}

template<typename TA, bool RELU, bool ACC>
static void launch_g(hipStream_t st, const TA* A, int lda, const float* W, int ldb,
                     const float* bias, float* C, int ldc, int M, int N, int K)
{
    dim3 grid((M + 31) / 32, (N + 31) / 32, 1);
    ngemm<TA, RELU, ACC><<<grid, 256, 0, st>>>(A, lda, W, ldb, bias, C, ldc, M, N, K);
}

// -- value GEMM, fused NCHW->token gather (batch b, channels [c0,c0+64)) ------
__global__ __launch_bounds__(256)
void value_ngemm(const float* __restrict__ s0, const float* __restrict__ s1,
                 const float* __restrict__ s2, const float* __restrict__ s3,
                 int b, const float* __restrict__ W, const float* __restrict__ bias,
                 float* __restrict__ outv, int c0)
{
    __shared__ double As[32][33];
    __shared__ double Bs[32][33];
    int bm = blockIdx.x * 32, bn = blockIdx.y * 32;
    int tx = threadIdx.x & 15, ty = threadIdx.x >> 4;
    double a00 = 0., a01 = 0., a10 = 0., a11 = 0.;
    for (int k0 = 0; k0 < 256; k0 += 32) {
        for (int e = threadIdx.x; e < 1024; e += 256) {
            int r = e >> 5, kk = e & 31;
            int t = bm + r; if (t > SSP - 1) t = SSP - 1;
            const float* sb; int hw, s;
            if (t < 10000)      { sb = s0; hw = 10000; s = t; }
            else if (t < 12500) { sb = s1; hw = 2500;  s = t - 10000; }
            else if (t < 13125) { sb = s2; hw = 625;   s = t - 12500; }
            else                { sb = s3; hw = 169;   s = t - 13125; }
            As[r][kk] = (double)sb[(size_t)(b * 256 + k0 + kk) * hw + s];
            Bs[r][kk] = (double)W[(size_t)(c0 + bn + r) * 256 + k0 + kk];
        }
        __syncthreads();
        for (int kk = 0; kk < 32; kk++) {
            double x0 = As[ty * 2][kk], x1 = As[ty * 2 + 1][kk];
            double y0 = Bs[tx * 2][kk], y1 = Bs[tx * 2 + 1][kk];
            a00 += x0 * y0; a01 += x0 * y1;
            a10 += x1 * y0; a11 += x1 * y1;
        }
        __syncthreads();
    }
    double accv[2][2] = {{a00, a01}, {a10, a11}};
    for (int i = 0; i < 2; i++)
        for (int j = 0; j < 2; j++) {
            int gm = bm + ty * 2 + i, gn = bn + tx * 2 + j;
            if (gm < SSP)
                outv[(size_t)gm * 64 + gn] = (float)(accv[i][j] + (double)bias[c0 + gn]);
        }
}

// ---------------- naive MHA, fp64 math: one block per (b*300+q, h) ------------
__global__ __launch_bounds__(320)
void naive_mha(const float* __restrict__ qk, const float* __restrict__ vbuf,
               float* __restrict__ mha)
{
    int row = blockIdx.x;
    int b = row / 300;
    int h = blockIdx.y;
    const double scale = 0.17677669529663687;
    __shared__ double sc[304];
    __shared__ double red[2];
    int j = threadIdx.x;
    if (j < 300) {
        const float* qp = qk + (size_t)row * 512 + h * 32;
        const float* kp = qk + (size_t)(b * 300 + j) * 512 + 256 + h * 32;
        double s = 0.;
        for (int d = 0; d < 32; d++) s += (double)qp[d] * (double)kp[d];
        sc[j] = s;
    }
    __syncthreads();
    if (threadIdx.x == 0) {
        double mx = -1e300;
        for (int t = 0; t < 300; t++) mx = fmax(mx, sc[t]);
        double sm = 0.;
        for (int t = 0; t < 300; t++) sm += exp((sc[t] - mx) * scale);
        red[0] = mx; red[1] = sm;
    }
    __syncthreads();
    if (j < 300) sc[j] = exp((sc[j] - red[0]) * scale) / red[1];
    __syncthreads();
    if (j < 32) {
        double o = 0.;
        const float* vp = vbuf + (size_t)(b * 300) * 256 + h * 32 + j;
        for (int t = 0; t < 300; t++) o += sc[t] * (double)vp[(size_t)t * 256];
        mha[(size_t)row * 256 + h * 32 + j] = (float)o;
    }
}

// ---------------- small-N GEMMs, fp64 math ------------------------------------
__global__ __launch_bounds__(256)
void gemm_small_qe(const float* __restrict__ qe, const float* __restrict__ W,
                   const float* __restrict__ bias, float* __restrict__ out, int N, int M)
{
    int t = blockIdx.x * 256 + threadIdx.x;
    if (t >= M * N) return;
    int row = t / N, n = t % N;
    const float* a = qe + (size_t)(row % 300) * 512;   // qpos = query_embed[:, :256]
    const float* w = W + (size_t)n * 256;
    double s = 0.0;
    for (int k = 0; k < 256; k++) s += (double)a[k] * (double)w[k];
    out[t] = (float)(s + (double)bias[n]);
}
__global__ __launch_bounds__(256)
void gemm_smallN(const float* __restrict__ A, int lda, const float* __restrict__ W,
                 const float* __restrict__ bias, float* __restrict__ out, int N, int M)
{
    int t = blockIdx.x * 256 + threadIdx.x;
    if (t >= M * N) return;
    int row = t / N, n = t % N;
    const float* a = A + (size_t)row * lda;
    const float* w = W + (size_t)n * 256;
    double s = 0.0;
    for (int k = 0; k < 256; k++) s += (double)a[k] * (double)w[k];
    out[t] = (float)(s + (double)bias[n]);
}

// ---------------- tgt init (fp64 residual stream) -----------------------------
__global__ __launch_bounds__(256)
void init_tgt(const float* __restrict__ qe, double* __restrict__ tgt)
{
    int row = blockIdx.x, c = threadIdx.x;
    size_t i = (size_t)row * 256 + c;
    tgt[i] = (row < NROW) ? (double)qe[(size_t)(row % 300) * 512 + 256 + c] : 0.0;
}

// qin = tgt + qpos (qpos read straight from query_embed)
__global__ void add_q(const double* __restrict__ tgt, const float* __restrict__ qe,
                      float* __restrict__ qin)
{
    int row = blockIdx.x, c = threadIdx.x;
    size_t i = (size_t)row * 256 + c;
    qin[i] = (float)(tgt[i] + (double)qe[(size_t)(row % 300) * 512 + c]);
}

// ---------------- fused residual-add + LayerNorm, fp64 math -------------------
__global__ __launch_bounds__(256)
void add_ln(double* __restrict__ tgt, const float* __restrict__ br,
            const float* __restrict__ w, const float* __restrict__ b,
            float* __restrict__ hs_out)
{
    int row = blockIdx.x, c = threadIdx.x;
    size_t idx = (size_t)row * 256 + c;
    double v = tgt[idx] + (double)br[idx];
    double s = v, s2 = v * v;
#pragma unroll
    for (int o = 32; o > 0; o >>= 1) { s += __shfl_xor(s, o); s2 += __shfl_xor(s2, o); }
    __shared__ double rs[4], rs2[4];
    int wv = c >> 6;
    if ((c & 63) == 0) { rs[wv] = s; rs2[wv] = s2; }
    __syncthreads();
    double S = rs[0] + rs[1] + rs[2] + rs[3];
    double S2 = rs2[0] + rs2[1] + rs2[2] + rs2[3];
    double mean = S * (1.0 / 256.0);
    double var = S2 * (1.0 / 256.0) - mean * mean;
    double o = (v - mean) / sqrt(var + 1e-5) * (double)w[c] + (double)b[c];
    tgt[idx] = o;
    if (hs_out) hs_out[idx] = (float)o;
}

// ---------------- attention-weight softmax over 16 per (row,h), fp64 ----------
__global__ __launch_bounds__(256)
void aw_softmax(float* __restrict__ buf)
{
    int t = blockIdx.x * 256 + threadIdx.x;
    if (t >= NROW * 8) return;
    int row = t >> 3, h = t & 7;
    float* p = buf + (size_t)row * 128 + h * 16;
    double mx = -1e300, e[16];
#pragma unroll
    for (int j = 0; j < 16; j++) mx = fmax(mx, (double)p[j]);
    double s = 0.;
#pragma unroll
    for (int j = 0; j < 16; j++) { e[j] = exp((double)p[j] - mx); s += e[j]; }
    double inv = 1.0 / s;
#pragma unroll
    for (int j = 0; j < 16; j++) p[j] = (float)(e[j] * inv);
}

// ------ deformable bilinear sampler, fp64 math, value slice 64 ch (2 heads) ----
__global__ __launch_bounds__(64)
void deform_sample(const float* __restrict__ value, int h0,
                   const float* __restrict__ offb, const float* __restrict__ awsm,
                   const double* __restrict__ ref, float* __restrict__ out, int row0)
{
    int row = row0 + blockIdx.x;
    int hl = threadIdx.x >> 5, d = threadIdx.x & 31;
    int h = h0 + hl;
    double rx = ref[row * 4 + 0], ry = ref[row * 4 + 1];
    double rw = ref[row * 4 + 2], rh = ref[row * 4 + 3];
    const float* offr = offb + (size_t)row * 256;
    const float* awr = awsm + (size_t)row * 128 + h * 16;
    size_t vbase = hl * 32 + d;
    const int LH[4] = {100, 50, 25, 13};
    const int LW[4] = {100, 50, 25, 13};
    const int LS[4] = {0, 10000, 12500, 13125};
    double acc = 0.;
#pragma unroll
    for (int l = 0; l < 4; l++) {
        int Hh = LH[l], Ww = LW[l], st = LS[l];
#pragma unroll
        for (int p = 0; p < 4; p++) {
            double ox = (double)offr[(h * 32) + l * 8 + p * 2 + 0];
            double oy = (double)offr[(h * 32) + l * 8 + p * 2 + 1];
            double aw = (double)awr[l * 4 + p];
            double x = (rx + ox * 0.125 * rw) * Ww - 0.5;
            double y = (ry + oy * 0.125 * rh) * Hh - 0.5;
            double xf = floor(x), yf = floor(y);
            double dx = x - xf, dy = y - yf;
            int x0 = (int)xf, y0 = (int)yf;
            double w00 = (1 - dx) * (1 - dy), w10 = dx * (1 - dy);
            double w01 = (1 - dx) * dy, w11 = dx * dy;
#define CORN(X, Y, W)                                                              \
            if ((unsigned)(X) < (unsigned)Ww && (unsigned)(Y) < (unsigned)Hh)      \
                acc += (W) * aw * (double)value[vbase + (size_t)(st + (Y) * Ww + (X)) * 64];
            CORN(x0, y0, w00) CORN(x0 + 1, y0, w10) CORN(x0, y0 + 1, w01) CORN(x0 + 1, y0 + 1, w11)
#undef CORN
        }
    }
    out[(size_t)row * 256 + h * 32 + d] = (float)acc;
}

// ---------------- ref init / update (fp64 state, fp32 refs out) ---------------
__global__ void ref_init(const float* __restrict__ lin2, const float* __restrict__ bb,
                         double* __restrict__ ref)
{
    int t = blockIdx.x * 256 + threadIdx.x;
    if (t >= NROW) return;
#pragma unroll
    for (int j = 0; j < 2; j++) {
        double r2 = sigd((double)lin2[t * 2 + j]);
        ref[t * 4 + j] = sigd((double)bb[t * 4 + j] + invsigd(r2));
    }
    ref[t * 4 + 2] = sigd((double)bb[t * 4 + 2]);
    ref[t * 4 + 3] = sigd((double)bb[t * 4 + 3]);
}
__global__ void ref_update(const float* __restrict__ bb, double* __restrict__ ref,
                           float* __restrict__ refs_out)
{
    int t = blockIdx.x * 256 + threadIdx.x;
    if (t >= NROW * 4) return;
    double nv = sigd((double)bb[t] + invsigd(ref[t]));
    ref[t] = nv;
    refs_out[t] = (float)nv;
}

// =============================== launcher =====================================
extern "C" void kernel_launch(void* const* d_in, const int* in_sizes, int n_in,
                              void* d_out, int out_size, void* d_ws, size_t ws_size,
                              hipStream_t stream)
{
    const float* src0 = (const float*)d_in[0];
    const float* src1 = (const float*)d_in[2];
    const float* src2 = (const float*)d_in[4];
    const float* src3 = (const float*)d_in[6];
    const float* qe = (const float*)d_in[8];
    const float* ref_w = (const float*)d_in[9];
    const float* ref_b = (const float*)d_in[10];
    const float* sa_in_w = (const float*)d_in[11];
    const float* sa_in_b = (const float*)d_in[12];
    const float* sa_out_w = (const float*)d_in[13];
    const float* sa_out_b = (const float*)d_in[14];
    const float* off_w = (const float*)d_in[15];
    const float* off_b = (const float*)d_in[16];
    const float* aw_w = (const float*)d_in[17];
    const float* aw_b = (const float*)d_in[18];
    const float* val_w = (const float*)d_in[19];
    const float* val_b = (const float*)d_in[20];
    const float* cao_w = (const float*)d_in[21];
    const float* cao_b = (const float*)d_in[22];
    const float* ln1_w = (const float*)d_in[23];
    const float* ln1_b = (const float*)d_in[24];
    const float* ln2_w = (const float*)d_in[25];
    const float* ln2_b = (const float*)d_in[26];
    const float* ln3_w = (const float*)d_in[27];
    const float* ln3_b = (const float*)d_in[28];
    const float* ff1_w = (const float*)d_in[29];
    const float* ff1_b = (const float*)d_in[30];
    const float* ff2_w = (const float*)d_in[31];
    const float* ff2_b = (const float*)d_in[32];
    const float* bb_w1 = (const float*)d_in[33];
    const float* bb_b1 = (const float*)d_in[34];
    const float* bb_w2 = (const float*)d_in[35];
    const float* bb_b2 = (const float*)d_in[36];
    const float* bb_w3 = (const float*)d_in[37];
    const float* bb_b3 = (const float*)d_in[38];
    const float* cls_w = (const float*)d_in[39];
    const float* cls_b = (const float*)d_in[40];

    char* wsp = (char*)d_ws;
    size_t off_ws = 0;
    auto alloc = [&](size_t bytes) -> char* {
        char* p = wsp + off_ws;
        off_ws += (bytes + 255) & ~(size_t)255;
        return p;
    };
    // lean layout, ~21.0 MB total (ws >= 23 MB proven by round-7 probe)
    float* value = (float*)alloc((size_t)SSP * 64 * 4);      // 3.40 MB (batch, 64-ch slice)
    double* tgt  = (double*)alloc((size_t)NROWP * 256 * 8);  // 4.98 MB fp64 residual stream
    float* proj = (float*)alloc((size_t)NROWP * 256 * 4);    // 2.49
    char* bigA = alloc((size_t)NROWP * 512 * 4);             // 4.98 union
    float* qk   = (float*)bigA;                              //  qk 512 (self-attn)
    float* ffnh = (float*)bigA;                              //  ffnh 512-split (FFN)
    float* offb = (float*)bigA;                              //  offb 256 (deform)
    float* awb  = (float*)(bigA + (size_t)NROWP * 256 * 4);  //  awb 128 (deform)
    char* bufB = alloc((size_t)NROWP * 256 * 4);             // 2.49 union
    float* vbuf = (float*)bufB;
    float* samp = (float*)bufB;
    float* bh1  = (float*)bufB;
    char* bufC = alloc((size_t)NROWP * 256 * 4);             // 2.49 union
    float* qin = (float*)bufC;
    float* mha = (float*)bufC;
    float* bh2 = (float*)bufC;
    float* bb4   = (float*)alloc((size_t)NROWP * 4 * 4);
    double* refb = (double*)alloc((size_t)NROWP * 4 * 8);
    float* rlin2 = (float*)alloc((size_t)NROWP * 2 * 4);

    float* out_f = (float*)d_out;                            // fp32 outputs
    float* hs_out = out_f;                                   // 6 * 614400
    float* refs_out = out_f + (size_t)6 * 614400;            // 6 * 9600
    float* log_out = refs_out + (size_t)6 * 9600;            // 6 * 194400

    // ---- setup ----
    init_tgt<<<NROWP, 256, 0, stream>>>(qe, tgt);
    gemm_small_qe<<<(NROW * 2 + 255) / 256, 256, 0, stream>>>(qe, ref_w, ref_b, rlin2, 2, NROW);
    launch_g<double, true, false>(stream, tgt, 256, bb_w1, 256, bb_b1, bh1, 256, NROW, 256, 256);
    launch_g<float, true, false>(stream, bh1, 256, bb_w2, 256, bb_b2, proj, 256, NROW, 256, 256);
    gemm_smallN<<<(NROW * 4 + 255) / 256, 256, 0, stream>>>(proj, 256, bb_w3, bb_b3, bb4, 4, NROW);
    ref_init<<<(NROW + 255) / 256, 256, 0, stream>>>(rlin2, bb4, refb);

    for (int i = 0; i < 6; i++) {
        // ---- self attention: qin(bufC) -> qk(bigA); vbuf(bufB); mha(bufC over qin) ----
        add_q<<<NROW, 256, 0, stream>>>(tgt, qe, qin);
        launch_g<float, false, false>(stream, qin, 256, sa_in_w + (size_t)i * 196608, 256,
                                      sa_in_b + i * 768, qk, 512, NROW, 512, 256);
        launch_g<double, false, false>(stream, tgt, 256, sa_in_w + (size_t)i * 196608 + 131072, 256,
                                       sa_in_b + i * 768 + 512, vbuf, 256, NROW, 256, 256);
        naive_mha<<<dim3(NROW, 8), 320, 0, stream>>>(qk, vbuf, mha);
        launch_g<float, false, false>(stream, mha, 256, sa_out_w + (size_t)i * 65536, 256,
                                      sa_out_b + i * 256, proj, 256, NROW, 256, 256);
        add_ln<<<NROW, 256, 0, stream>>>(tgt, proj, ln2_w + i * 256, ln2_b + i * 256, nullptr);

        // ---- deformable cross attention: qin(bufC), offb/awb(bigA), samp(bufB) ----
        add_q<<<NROW, 256, 0, stream>>>(tgt, qe, qin);
        launch_g<float, false, false>(stream, qin, 256, off_w + (size_t)i * 65536, 256,
                                      off_b + i * 256, offb, 256, NROW, 256, 256);
        launch_g<float, false, false>(stream, qin, 256, aw_w + (size_t)i * 32768, 256,
                                      aw_b + i * 128, awb, 128, NROW, 128, 256);
        aw_softmax<<<(NROW * 8 + 255) / 256, 256, 0, stream>>>(awb);
        for (int b = 0; b < 8; b++) {
            for (int s = 0; s < 4; s++) {
                value_ngemm<<<dim3((SSP + 31) / 32, 2), 256, 0, stream>>>(
                    src0, src1, src2, src3, b, val_w + (size_t)i * 65536, val_b + i * 256,
                    value, s * 64);
                deform_sample<<<300, 64, 0, stream>>>(value, s * 2, offb, awb, refb,
                                                      samp, b * 300);
            }
        }
        launch_g<float, false, false>(stream, samp, 256, cao_w + (size_t)i * 65536, 256,
                                      cao_b + i * 256, proj, 256, NROW, 256, 256);
        add_ln<<<NROW, 256, 0, stream>>>(tgt, proj, ln1_w + i * 256, ln1_b + i * 256, nullptr);

        // ---- FFN, hidden split 2x512 into ffnh(bigA) ----
        launch_g<double, true, false>(stream, tgt, 256, ff1_w + (size_t)i * 262144, 256,
                                      ff1_b + i * 1024, ffnh, 512, NROW, 512, 256);
        launch_g<float, false, false>(stream, ffnh, 512, ff2_w + (size_t)i * 262144, 1024,
                                      ff2_b + i * 256, proj, 256, NROW, 256, 512);
        launch_g<double, true, false>(stream, tgt, 256, ff1_w + (size_t)i * 262144 + 512 * 256, 256,
                                      ff1_b + i * 1024 + 512, ffnh, 512, NROW, 512, 256);
        launch_g<float, false, true>(stream, ffnh, 512, ff2_w + (size_t)i * 262144 + 512, 1024,
                                     nullptr, proj, 256, NROW, 256, 512);
        add_ln<<<NROW, 256, 0, stream>>>(tgt, proj, ln3_w + i * 256, ln3_b + i * 256,
                                         hs_out + (size_t)i * 614400);

        // ---- bbox refinement: bh1(bufB), bh2(bufC) ----
        launch_g<double, true, false>(stream, tgt, 256, bb_w1 + (size_t)(i + 1) * 65536, 256,
                                      bb_b1 + (i + 1) * 256, bh1, 256, NROW, 256, 256);
        launch_g<float, true, false>(stream, bh1, 256, bb_w2 + (size_t)(i + 1) * 65536, 256,
                                     bb_b2 + (i + 1) * 256, bh2, 256, NROW, 256, 256);
        gemm_smallN<<<(NROW * 4 + 255) / 256, 256, 0, stream>>>(
            bh2, 256, bb_w3 + (size_t)(i + 1) * 1024, bb_b3 + (i + 1) * 4, bb4, 4, NROW);
        ref_update<<<(NROW * 4 + 255) / 256, 256, 0, stream>>>(bb4, refb, refs_out + (size_t)i * 9600);

        // ---- logits ----
        launch_g<double, false, false>(stream, tgt, 256, cls_w + (size_t)(i + 1) * 20736, 256,
                                       cls_b + (i + 1) * 81, log_out + (size_t)i * 194400,
                                       81, NROW, 81, 256);
    }
}